// Round 1
// baseline (388.295 us; speedup 1.0000x reference)
//
#include <hip/hip_runtime.h>
#include <hip/hip_bf16.h>

// ---------------------------------------------------------------------------
// InferCellV2: 3-node cell, 6 convs (3x3, C=64, B=128, H=W=32, SAME).
//   node1 = conv(relu(x), W0*scale)
//   node2 = conv(relu(x), W1*s) + conv(relu(node1), W2*s)
//   node3 = conv(relu(x), W3*s) + conv(relu(node1), W4*s) + conv(relu(node2), W5*s)
// Strategy: bf16 MFMA implicit GEMM (fp32 accum). Activations in zero-padded
// NHWC bf16 [B][34][34][64] so tap shifts are plain address offsets (no
// predication) and channel dim is contiguous (K-contiguous A fragments).
// Weights folded with scale and transposed to [l][tap][o][i] bf16.
// ---------------------------------------------------------------------------

typedef __bf16 bf16x8 __attribute__((ext_vector_type(8)));
typedef float floatx4 __attribute__((ext_vector_type(4)));
typedef unsigned int uint32;

#define PADW 34
#define PIMG (PADW * PADW)          // 1156 padded pixels per image
#define RBYTES ((size_t)128 * PIMG * 64 * 2)  // one padded NHWC bf16 buffer

// ---------------- weight prep: fold rank-1 channel scale, transpose ---------
// wt[l][t][o][i] = bf16( W[l][o][i][t] * a_out[o] * a_in[i] )
__global__ void prep_weights(const float* __restrict__ a1,
                             const float* __restrict__ a2,
                             const float* __restrict__ W,
                             __hip_bfloat16* __restrict__ wt) {
    int idx = blockIdx.x * 256 + threadIdx.x;   // 6*9*64*64 = 221184 exact
    int i = idx & 63;
    int o = (idx >> 6) & 63;
    int rest = idx >> 12;                        // 0..53
    int t = rest % 9;
    int l = rest / 9;
    // a_in[i] = sum_{j >= i>>3} alphas1[j]  (channel i inside widths 8(j+1)>i)
    int ji = i >> 3, jo = o >> 3;
    float ain = 0.f, aout = 0.f;
#pragma unroll
    for (int j = 0; j < 8; ++j) {
        ain  += (j >= ji) ? a1[j] : 0.f;
        aout += (j >= jo) ? a2[j] : 0.f;
    }
    float v = W[(size_t)((l * 64 + o) * 64 + i) * 9 + t] * ain * aout;
    wt[(size_t)((l * 9 + t) * 64 + o) * 64 + i] = __float2bfloat16(v);
}

// ---------------- relu(x) -> padded NHWC bf16 (interior only) ---------------
// One block per (b, y): LDS-transpose NCHW[64][32] -> NHWC[32][64].
__global__ void relu_pad(const float* __restrict__ in,
                         __hip_bfloat16* __restrict__ r0) {
    __shared__ float tile[32][65];               // +1 pad: conflict-free
    int b = blockIdx.x >> 5, y = blockIdx.x & 31;
    int tid = threadIdx.x;
    int x = tid & 31, c0 = tid >> 5;             // read phase: lanes = x
    const float* ip = in + ((size_t)b * 64 * 32 + y) * 32 + x;
#pragma unroll
    for (int cc = 0; cc < 8; ++cc) {
        int c = cc * 8 + c0;
        tile[x][c] = fmaxf(ip[(size_t)c * 1024], 0.f);
    }
    __syncthreads();
    int o = tid & 63, xg = tid >> 6;             // write phase: lanes = c
    __hip_bfloat16* op = r0 + ((size_t)(b * PADW + y + 1) * PADW + 1) * 64 + o;
#pragma unroll
    for (int xx = 0; xx < 8; ++xx) {
        int xq = xx * 4 + xg;
        op[(size_t)xq * 64] = __float2bfloat16(tile[xq][o]);
    }
}

// ---------------- zero the halo ring of all three activation buffers --------
__global__ void zero_halo(__hip_bfloat16* r0, __hip_bfloat16* r1,
                          __hip_bfloat16* r2) {
    int b = blockIdx.x;
    int tid = threadIdx.x;
    __hip_bfloat16* bufs[3] = {r0, r1, r2};
#pragma unroll
    for (int f = 0; f < 3; ++f) {
        uint32* buf = (uint32*)(bufs[f] + (size_t)b * PIMG * 64);
        for (int idx = tid; idx < 132 * 32; idx += 256) {  // 132 halo slots * 32 dwords
            int slot = idx >> 5, u = idx & 31;
            int yy, xx;
            if (slot < 34)      { yy = 0;  xx = slot; }
            else if (slot < 68) { yy = 33; xx = slot - 34; }
            else { int s2 = slot - 68; yy = 1 + (s2 >> 1); xx = (s2 & 1) * 33; }
            buf[(size_t)(yy * PADW + xx) * 32 + u] = 0u;
        }
    }
}

// ---------------- conv stage: implicit GEMM via 9 shifted GEMMs -------------
// Block = 256 threads = 4 waves = (b, 4-row strip). Wave w computes image row
// y0+w: 32 pixels x 64 out-channels = 2 Mtiles x 4 Ntiles of 16x16x32 MFMA.
// A frag: lane&15 = pixel col (+16 per mtile), quad*8+j = channel.
// B frag: lane&15 = out channel (+16 per ntile), quad*8+j = in channel.
template <int NSRC, bool FINAL>
__global__ __launch_bounds__(256) void conv_stage(
    const __hip_bfloat16* __restrict__ s0,
    const __hip_bfloat16* __restrict__ s1,
    const __hip_bfloat16* __restrict__ s2,
    const __hip_bfloat16* __restrict__ wt,
    void* __restrict__ dstv, int l0) {
    int tid = threadIdx.x;
    int wave = tid >> 6, lane = tid & 63;
    int quad = lane >> 4, l15 = lane & 15;
    int blk = blockIdx.x;
    int b = blk >> 3;
    int y = ((blk & 7) << 2) + wave;             // image row for this wave

    floatx4 acc[2][4];
#pragma unroll
    for (int a = 0; a < 2; ++a)
#pragma unroll
        for (int n = 0; n < 4; ++n) acc[a][n] = (floatx4){0.f, 0.f, 0.f, 0.f};

#pragma unroll
    for (int s = 0; s < NSRC; ++s) {
        const __hip_bfloat16* src = (s == 0) ? s0 : (s == 1) ? s1 : s2;
        const __hip_bfloat16* wb =
            wt + (size_t)(l0 + s) * 9 * 4096 + (size_t)l15 * 64;
#pragma unroll
        for (int ky = 0; ky < 3; ++ky) {
            // padded row = image_y + ky  (since pad offset +1, tap dy = ky-1)
            const __hip_bfloat16* srow =
                src + ((size_t)(b * PADW + y + ky) * PADW + l15) * 64;
#pragma unroll
            for (int kx = 0; kx < 3; ++kx) {
                const __hip_bfloat16* ap = srow + kx * 64;
                const __hip_bfloat16* wp = wb + (ky * 3 + kx) * 4096;
#pragma unroll
                for (int q = 0; q < 2; ++q) {
                    int ko = q * 32 + quad * 8;
                    bf16x8 A0 = *(const bf16x8*)(ap + ko);
                    bf16x8 A1 = *(const bf16x8*)(ap + 16 * 64 + ko);
                    bf16x8 B0 = *(const bf16x8*)(wp + ko);
                    bf16x8 B1 = *(const bf16x8*)(wp + 1024 + ko);
                    bf16x8 B2 = *(const bf16x8*)(wp + 2048 + ko);
                    bf16x8 B3 = *(const bf16x8*)(wp + 3072 + ko);
                    acc[0][0] = __builtin_amdgcn_mfma_f32_16x16x32_bf16(A0, B0, acc[0][0], 0, 0, 0);
                    acc[0][1] = __builtin_amdgcn_mfma_f32_16x16x32_bf16(A0, B1, acc[0][1], 0, 0, 0);
                    acc[0][2] = __builtin_amdgcn_mfma_f32_16x16x32_bf16(A0, B2, acc[0][2], 0, 0, 0);
                    acc[0][3] = __builtin_amdgcn_mfma_f32_16x16x32_bf16(A0, B3, acc[0][3], 0, 0, 0);
                    acc[1][0] = __builtin_amdgcn_mfma_f32_16x16x32_bf16(A1, B0, acc[1][0], 0, 0, 0);
                    acc[1][1] = __builtin_amdgcn_mfma_f32_16x16x32_bf16(A1, B1, acc[1][1], 0, 0, 0);
                    acc[1][2] = __builtin_amdgcn_mfma_f32_16x16x32_bf16(A1, B2, acc[1][2], 0, 0, 0);
                    acc[1][3] = __builtin_amdgcn_mfma_f32_16x16x32_bf16(A1, B3, acc[1][3], 0, 0, 0);
                }
            }
        }
    }

    // Epilogue. C/D layout: col(lane&15)=out-channel n, row(quad*4+r)=pixel m.
    if (FINAL) {
        float* out = (float*)dstv;   // fp32 NCHW [128][64][32][32]
#pragma unroll
        for (int a = 0; a < 2; ++a)
#pragma unroll
            for (int n = 0; n < 4; ++n)
#pragma unroll
                for (int r = 0; r < 4; ++r) {
                    int col = a * 16 + quad * 4 + r;
                    int o = n * 16 + l15;
                    out[(((size_t)b * 64 + o) * 32 + y) * 32 + col] = acc[a][n][r];
                }
    } else {
        __hip_bfloat16* out = (__hip_bfloat16*)dstv;  // relu -> padded NHWC
#pragma unroll
        for (int a = 0; a < 2; ++a)
#pragma unroll
            for (int n = 0; n < 4; ++n)
#pragma unroll
                for (int r = 0; r < 4; ++r) {
                    int col = a * 16 + quad * 4 + r;
                    int o = n * 16 + l15;
                    float v = fmaxf(acc[a][n][r], 0.f);
                    out[((size_t)(b * PADW + y + 1) * PADW + col + 1) * 64 + o] =
                        __float2bfloat16(v);
                }
    }
}

// ---------------------------------------------------------------------------
extern "C" void kernel_launch(void* const* d_in, const int* in_sizes, int n_in,
                              void* d_out, int out_size, void* d_ws,
                              size_t ws_size, hipStream_t stream) {
    const float* inputs  = (const float*)d_in[0];
    const float* alphas1 = (const float*)d_in[1];
    const float* alphas2 = (const float*)d_in[2];
    const float* W       = (const float*)d_in[3];
    char* ws = (char*)d_ws;

    __hip_bfloat16* wt = (__hip_bfloat16*)(ws);                     // 442 KB
    __hip_bfloat16* r0 = (__hip_bfloat16*)(ws + ((size_t)1 << 20)); // 18.1 MB
    __hip_bfloat16* r1 = (__hip_bfloat16*)(ws + ((size_t)20 << 20));
    __hip_bfloat16* r2 = (__hip_bfloat16*)(ws + ((size_t)40 << 20));
    float* out = (float*)d_out;

    prep_weights<<<864, 256, 0, stream>>>(alphas1, alphas2, W, wt);
    relu_pad<<<128 * 32, 256, 0, stream>>>(inputs, r0);
    zero_halo<<<128, 256, 0, stream>>>(r0, r1, r2);

    conv_stage<1, false><<<1024, 256, 0, stream>>>(r0, r1, r2, wt, (void*)r1, 0);
    conv_stage<2, false><<<1024, 256, 0, stream>>>(r0, r1, r2, wt, (void*)r2, 1);
    conv_stage<3, true ><<<1024, 256, 0, stream>>>(r0, r1, r2, wt, (void*)out, 3);
}

// Round 2
// 193.607 us; speedup vs baseline: 2.0056x; 2.0056x over previous
//
#include <hip/hip_runtime.h>
#include <hip/hip_bf16.h>

// ---------------------------------------------------------------------------
// InferCellV2 R2: bf16 MFMA implicit GEMM with LDS-staged operands.
// Activations: zero-padded NHWC bf16 [B][34][34][64]. Weights folded with
// rank-1 channel scale, transposed to [l][tap][o][i] bf16.
// conv_stage: block = 128 thr (2 waves) = 4 output rows of one image.
//   LDS = 6 padded act rows (26112 B) + 3 weight taps (24576 B) = 50688 B.
//   Wave tile = 64 px (2 rows) x 64 oc = 4x4 MFMA tiles, 64 acc VGPRs.
//   Both A and B staged via global_load_lds(16B), frags via ds_read_b128.
// ---------------------------------------------------------------------------

typedef __bf16 bf16x8 __attribute__((ext_vector_type(8)));
typedef float floatx4 __attribute__((ext_vector_type(4)));
typedef unsigned int uint32;

#define PADW 34
#define PIMG (PADW * PADW)          // 1156 padded pixels per image
#define ROWB (PADW * 64 * 2)        // 4352 bytes per padded NHWC row
#define A_BYTES (6 * ROWB)          // 26112
#define B_BYTES (3 * 64 * 64 * 2)   // 24576 (3 taps)
#define A_CHUNKS (A_BYTES / 16)     // 1632
#define B_CHUNKS (B_BYTES / 16)     // 1536

__device__ __forceinline__ void gld16(const char* g, char* l) {
    __builtin_amdgcn_global_load_lds(
        (const __attribute__((address_space(1))) uint32*)g,
        (__attribute__((address_space(3))) uint32*)l, 16, 0, 0);
}

// ---------------- weight prep: fold rank-1 channel scale, transpose ---------
// wt[l][t][o][i] = bf16( W[l][o][i][t] * a_out[o] * a_in[i] )
__global__ void prep_weights(const float* __restrict__ a1,
                             const float* __restrict__ a2,
                             const float* __restrict__ W,
                             __hip_bfloat16* __restrict__ wt) {
    int idx = blockIdx.x * 256 + threadIdx.x;   // 6*9*64*64 = 221184 exact
    int i = idx & 63;
    int o = (idx >> 6) & 63;
    int rest = idx >> 12;                        // 0..53
    int t = rest % 9;
    int l = rest / 9;
    int ji = i >> 3, jo = o >> 3;
    float ain = 0.f, aout = 0.f;
#pragma unroll
    for (int j = 0; j < 8; ++j) {
        ain  += (j >= ji) ? a1[j] : 0.f;
        aout += (j >= jo) ? a2[j] : 0.f;
    }
    float v = W[(size_t)((l * 64 + o) * 64 + i) * 9 + t] * ain * aout;
    wt[(size_t)((l * 9 + t) * 64 + o) * 64 + i] = __float2bfloat16(v);
}

// ---------------- relu(x) -> padded NHWC bf16 (interior only) ---------------
__global__ void relu_pad(const float* __restrict__ in,
                         __hip_bfloat16* __restrict__ r0) {
    __shared__ float tile[32][65];
    int b = blockIdx.x >> 5, y = blockIdx.x & 31;
    int tid = threadIdx.x;
    int x = tid & 31, c0 = tid >> 5;
    const float* ip = in + ((size_t)b * 64 * 32 + y) * 32 + x;
#pragma unroll
    for (int cc = 0; cc < 8; ++cc) {
        int c = cc * 8 + c0;
        tile[x][c] = fmaxf(ip[(size_t)c * 1024], 0.f);
    }
    __syncthreads();
    int o = tid & 63, xg = tid >> 6;
    __hip_bfloat16* op = r0 + ((size_t)(b * PADW + y + 1) * PADW + 1) * 64 + o;
#pragma unroll
    for (int xx = 0; xx < 8; ++xx) {
        int xq = xx * 4 + xg;
        op[(size_t)xq * 64] = __float2bfloat16(tile[xq][o]);
    }
}

// ---------------- zero the halo ring of all three activation buffers --------
__global__ void zero_halo(__hip_bfloat16* r0, __hip_bfloat16* r1,
                          __hip_bfloat16* r2) {
    int b = blockIdx.x;
    int tid = threadIdx.x;
    __hip_bfloat16* bufs[3] = {r0, r1, r2};
#pragma unroll
    for (int f = 0; f < 3; ++f) {
        uint32* buf = (uint32*)(bufs[f] + (size_t)b * PIMG * 64);
        for (int idx = tid; idx < 132 * 32; idx += 256) {
            int slot = idx >> 5, u = idx & 31;
            int yy, xx;
            if (slot < 34)      { yy = 0;  xx = slot; }
            else if (slot < 68) { yy = 33; xx = slot - 34; }
            else { int s2 = slot - 68; yy = 1 + (s2 >> 1); xx = (s2 & 1) * 33; }
            buf[(size_t)(yy * PADW + xx) * 32 + u] = 0u;
        }
    }
}

// ---------------- conv stage: LDS-staged implicit GEMM ----------------------
// Block 128 thr = 2 waves; block = image b, rows y0..y0+3.
// Wave w: rows y0+2w, y0+2w+1. A-frag: l15 = px, quad*8+q*32 = in-ch.
// B-frag: l15 = out-ch, quad*8+q*32 = in-ch. C/D: M(px)=quad*4+r, N(oc)=l15.
template <int NSRC, bool FINAL>
__global__ __launch_bounds__(128) void conv_stage(
    const __hip_bfloat16* __restrict__ s0,
    const __hip_bfloat16* __restrict__ s1,
    const __hip_bfloat16* __restrict__ s2,
    const __hip_bfloat16* __restrict__ wt,
    void* __restrict__ dstv, int l0) {
    __shared__ char smem[A_BYTES + B_BYTES];
    int tid = threadIdx.x;
    int wv = tid >> 6, lane = tid & 63;
    int quad = lane >> 4, l15 = lane & 15;
    int blk = blockIdx.x;
    int b = blk >> 3, y0 = (blk & 7) << 2;

    const char* srcs[3] = {(const char*)s0, (const char*)s1, (const char*)s2};

    floatx4 acc[4][4];
#pragma unroll
    for (int m = 0; m < 4; ++m)
#pragma unroll
        for (int n = 0; n < 4; ++n) acc[m][n] = (floatx4){0.f, 0.f, 0.f, 0.f};

#pragma unroll
    for (int s = 0; s < NSRC; ++s) {
        const char* gA = srcs[s] + ((size_t)b * PIMG + (size_t)y0 * PADW) * 128;
        const char* gW = (const char*)wt + (size_t)(l0 + s) * 9 * 8192;
#pragma unroll
        for (int ky = 0; ky < 3; ++ky) {
            __syncthreads();   // prior reads of smem complete before overwrite
            if (ky == 0) {     // stage 6 padded activation rows (contiguous)
#pragma unroll
                for (int it = 0; it < 13; ++it) {
                    int c = it * 128 + tid;
                    if (c < A_CHUNKS)
                        gld16(gA + (size_t)c * 16,
                              smem + (it * 128 + wv * 64) * 16);
                }
            }
            {                  // stage 3 weight taps for this ky (contiguous)
                const char* gB = gW + (size_t)(ky * 3) * 8192;
#pragma unroll
                for (int it = 0; it < 12; ++it) {
                    int c = it * 128 + tid;
                    gld16(gB + (size_t)c * 16,
                          smem + A_BYTES + (it * 128 + wv * 64) * 16);
                }
            }
            __syncthreads();   // vmcnt drained here (compiler before s_barrier)

#pragma unroll
            for (int kx = 0; kx < 3; ++kx)
#pragma unroll
                for (int q = 0; q < 2; ++q) {
                    bf16x8 Af[4], Bf[4];
#pragma unroll
                    for (int m = 0; m < 4; ++m) {
                        int arow = 2 * wv + (m >> 1) + ky;        // 0..5
                        int apx  = ((m & 1) << 4) + l15 + kx;     // 0..33
                        Af[m] = *(const bf16x8*)(smem + arow * ROWB +
                                                 apx * 128 + q * 64 + quad * 16);
                    }
#pragma unroll
                    for (int n = 0; n < 4; ++n)
                        Bf[n] = *(const bf16x8*)(smem + A_BYTES + kx * 8192 +
                                                 (((n << 4) + l15) * 128) +
                                                 q * 64 + quad * 16);
#pragma unroll
                    for (int m = 0; m < 4; ++m)
#pragma unroll
                        for (int n = 0; n < 4; ++n)
                            acc[m][n] = __builtin_amdgcn_mfma_f32_16x16x32_bf16(
                                Af[m], Bf[n], acc[m][n], 0, 0, 0);
                }
        }
    }

    // Epilogue. M(pixel) = quad*4+r (+16 per odd mtile), N(oc) = n*16+l15.
    if (FINAL) {
        float* out = (float*)dstv;   // fp32 NCHW [128][64][32][32]
#pragma unroll
        for (int m = 0; m < 4; ++m) {
            int row = y0 + 2 * wv + (m >> 1);
#pragma unroll
            for (int n = 0; n < 4; ++n) {
                int o = (n << 4) + l15;
#pragma unroll
                for (int r = 0; r < 4; ++r) {
                    int x = ((m & 1) << 4) + (quad << 2) + r;
                    out[(((size_t)b * 64 + o) * 32 + row) * 32 + x] = acc[m][n][r];
                }
            }
        }
    } else {
        __hip_bfloat16* out = (__hip_bfloat16*)dstv;  // relu -> padded NHWC
#pragma unroll
        for (int m = 0; m < 4; ++m) {
            int row = y0 + 2 * wv + (m >> 1);
#pragma unroll
            for (int n = 0; n < 4; ++n) {
                int o = (n << 4) + l15;
#pragma unroll
                for (int r = 0; r < 4; ++r) {
                    int x = ((m & 1) << 4) + (quad << 2) + r;
                    float v = fmaxf(acc[m][n][r], 0.f);
                    out[((size_t)(b * PADW + row + 1) * PADW + x + 1) * 64 + o] =
                        __float2bfloat16(v);
                }
            }
        }
    }
}

// ---------------------------------------------------------------------------
extern "C" void kernel_launch(void* const* d_in, const int* in_sizes, int n_in,
                              void* d_out, int out_size, void* d_ws,
                              size_t ws_size, hipStream_t stream) {
    const float* inputs  = (const float*)d_in[0];
    const float* alphas1 = (const float*)d_in[1];
    const float* alphas2 = (const float*)d_in[2];
    const float* W       = (const float*)d_in[3];
    char* ws = (char*)d_ws;

    __hip_bfloat16* wt = (__hip_bfloat16*)(ws);                     // 442 KB
    __hip_bfloat16* r0 = (__hip_bfloat16*)(ws + ((size_t)1 << 20)); // 18.1 MB
    __hip_bfloat16* r1 = (__hip_bfloat16*)(ws + ((size_t)20 << 20));
    __hip_bfloat16* r2 = (__hip_bfloat16*)(ws + ((size_t)40 << 20));
    float* out = (float*)d_out;

    prep_weights<<<864, 256, 0, stream>>>(alphas1, alphas2, W, wt);
    relu_pad<<<128 * 32, 256, 0, stream>>>(inputs, r0);
    zero_halo<<<128, 256, 0, stream>>>(r0, r1, r2);

    conv_stage<1, false><<<1024, 128, 0, stream>>>(r0, r1, r2, wt, (void*)r1, 0);
    conv_stage<2, false><<<1024, 128, 0, stream>>>(r0, r1, r2, wt, (void*)r2, 1);
    conv_stage<3, true ><<<1024, 128, 0, stream>>>(r0, r1, r2, wt, (void*)out, 3);
}

// Round 3
// 159.712 us; speedup vs baseline: 2.4312x; 1.2122x over previous
//
#include <hip/hip_runtime.h>
#include <hip/hip_bf16.h>

// ---------------------------------------------------------------------------
// InferCellV2 R3: bf16 MFMA implicit GEMM, LDS-staged, XOR-swizzled layout.
// Global activation layout: zero-padded NHWC bf16 [B][34][34][64] where the
// 8x16B channel-chunks of pixel p are permuted: chunk cb at p*128+((cb^(p&7))*16).
// Weight layout wt[l][tap][o][i] likewise swizzled by out-channel row o.
// => staging is a linear global_load_lds copy, and MFMA fragment ds_read_b128s
// (lane stride 128B) hit all 8 chunk slots across consecutive lanes: <=2-way
// bank aliasing (free) instead of ~8-way conflicts.
// conv_stage: 256 thr / 4 waves / 8 output rows / grid 512 (=2 blocks/CU, no
// tail). Per (src,ky): stage A 8 rows (34816B) + B 3 taps (24576B) = 58KB LDS.
// Wave tile 64px x 64oc = 4x4 MFMA 16x16x32, 64 acc VGPRs.
// ---------------------------------------------------------------------------

typedef __bf16 bf16x8 __attribute__((ext_vector_type(8)));
typedef float floatx4 __attribute__((ext_vector_type(4)));
typedef unsigned int uint32;

#define PADW 34
#define PIMG (PADW * PADW)
#define ROWB (PADW * 64 * 2)        // 4352 B per padded NHWC row
#define A_LDS (8 * ROWB)            // 34816
#define B_LDS (3 * 64 * 64 * 2)     // 24576
#define A_CHUNKS (A_LDS / 16)       // 2176
#define B_CHUNKS (B_LDS / 16)       // 1536

__device__ __forceinline__ void gld16(const char* g, char* l) {
    __builtin_amdgcn_global_load_lds(
        (const __attribute__((address_space(1))) uint32*)g,
        (__attribute__((address_space(3))) uint32*)l, 16, 0, 0);
}

// ---------------- weight prep: fold scale, transpose, swizzle ---------------
// chunk (i>>3) of row o stored at slot ((i>>3) ^ (o&7))
__global__ void prep_weights(const float* __restrict__ a1,
                             const float* __restrict__ a2,
                             const float* __restrict__ W,
                             __hip_bfloat16* __restrict__ wt) {
    int idx = blockIdx.x * 256 + threadIdx.x;   // 6*9*64*64 = 221184 exact
    int i = idx & 63;
    int o = (idx >> 6) & 63;
    int rest = idx >> 12;
    int t = rest % 9;
    int l = rest / 9;
    int ji = i >> 3, jo = o >> 3;
    float ain = 0.f, aout = 0.f;
#pragma unroll
    for (int j = 0; j < 8; ++j) {
        ain  += (j >= ji) ? a1[j] : 0.f;
        aout += (j >= jo) ? a2[j] : 0.f;
    }
    float v = W[(size_t)((l * 64 + o) * 64 + i) * 9 + t] * ain * aout;
    size_t e = (size_t)(l * 9 + t) * 4096 + o * 64 +
               ((((i >> 3) ^ (o & 7)) << 3) + (i & 7));
    wt[e] = __float2bfloat16(v);
}

// ---------------- relu(x) -> padded swizzled NHWC bf16 ----------------------
__global__ void relu_pad(const float* __restrict__ in,
                         __hip_bfloat16* __restrict__ r0) {
    __shared__ float tile[32][65];
    int b = blockIdx.x >> 5, y = blockIdx.x & 31;
    int tid = threadIdx.x;
    int x = tid & 31, c0 = tid >> 5;
    const float* ip = in + ((size_t)b * 64 * 32 + y) * 32 + x;
#pragma unroll
    for (int cc = 0; cc < 8; ++cc) {
        int c = cc * 8 + c0;
        tile[x][c] = fmaxf(ip[(size_t)c * 1024], 0.f);
    }
    __syncthreads();
    int o = tid & 63, xg = tid >> 6;
    int p0 = (b * PADW + y + 1) * PADW + 1;
#pragma unroll
    for (int xx = 0; xx < 8; ++xx) {
        int xq = xx * 4 + xg;
        int p = p0 + xq;
        size_t e = (size_t)p * 64 + ((((o >> 3) ^ (p & 7)) << 3) + (o & 7));
        r0[e] = __float2bfloat16(tile[xq][o]);
    }
}

// ---------------- zero halo ring (whole pixels; swizzle-agnostic) -----------
__global__ void zero_halo(__hip_bfloat16* r0, __hip_bfloat16* r1,
                          __hip_bfloat16* r2) {
    int b = blockIdx.x;
    int tid = threadIdx.x;
    __hip_bfloat16* bufs[3] = {r0, r1, r2};
#pragma unroll
    for (int f = 0; f < 3; ++f) {
        uint32* buf = (uint32*)(bufs[f] + (size_t)b * PIMG * 64);
        for (int idx = tid; idx < 132 * 32; idx += 256) {
            int slot = idx >> 5, u = idx & 31;
            int yy, xx;
            if (slot < 34)      { yy = 0;  xx = slot; }
            else if (slot < 68) { yy = 33; xx = slot - 34; }
            else { int s2 = slot - 68; yy = 1 + (s2 >> 1); xx = (s2 & 1) * 33; }
            buf[(size_t)(yy * PADW + xx) * 32 + u] = 0u;
        }
    }
}

// ---------------- conv stage ------------------------------------------------
// Block: image b = blk>>2, rows y0=(blk&3)*8 .. y0+7. Wave wv: rows y0+2wv,+1.
// A-frag: l15 = px, quad*8+q*32 = in-ch. B-frag: l15 = oc. C/D: M=quad*4+r.
template <int NSRC, bool FINAL>
__global__ __launch_bounds__(256) void conv_stage(
    const __hip_bfloat16* __restrict__ s0,
    const __hip_bfloat16* __restrict__ s1,
    const __hip_bfloat16* __restrict__ s2,
    const __hip_bfloat16* __restrict__ wt,
    void* __restrict__ dstv, int l0) {
    __shared__ char smem[A_LDS + B_LDS];        // 59392 B
    int tid = threadIdx.x;
    int wv = tid >> 6, lane = tid & 63;
    int quad = lane >> 4, l15 = lane & 15;
    int blk = blockIdx.x;
    int b = blk >> 2, y0 = (blk & 3) << 3;

    const char* srcs[3] = {(const char*)s0, (const char*)s1, (const char*)s2};

    floatx4 acc[4][4];
#pragma unroll
    for (int m = 0; m < 4; ++m)
#pragma unroll
        for (int n = 0; n < 4; ++n) acc[m][n] = (floatx4){0.f, 0.f, 0.f, 0.f};

#pragma unroll
    for (int s = 0; s < NSRC; ++s) {
        const char* gS = srcs[s];
        const char* gW = (const char*)wt + (size_t)(l0 + s) * 9 * 8192;
#pragma unroll
        for (int ky = 0; ky < 3; ++ky) {
            __syncthreads();   // prior compute reads done before overwrite
            {   // stage A: 8 padded rows y0+ky .. y0+ky+7 (linear copy)
                const char* gA = gS + (size_t)(b * PADW + y0 + ky) * PADW * 128;
#pragma unroll
                for (int it = 0; it < 9; ++it) {
                    int c = it * 256 + tid;
                    if (it < 8 || tid < A_CHUNKS - 2048)
                        gld16(gA + (size_t)c * 16,
                              smem + (it * 256 + wv * 64) * 16);
                }
            }
            {   // stage B: 3 taps for this ky (linear copy)
                const char* gB = gW + (size_t)(ky * 3) * 8192;
#pragma unroll
                for (int it = 0; it < 6; ++it) {
                    int c = it * 256 + tid;
                    gld16(gB + (size_t)c * 16,
                          smem + A_LDS + (it * 256 + wv * 64) * 16);
                }
            }
            __syncthreads();

#pragma unroll
            for (int kx = 0; kx < 3; ++kx)
#pragma unroll
                for (int q = 0; q < 2; ++q) {
                    bf16x8 Af[4], Bf[4];
#pragma unroll
                    for (int m = 0; m < 4; ++m) {
                        int arow = 2 * wv + (m >> 1);             // LDS row 0..7
                        int apx  = ((m & 1) << 4) + l15 + kx;     // 0..33
                        // global pixel phase: gp&7 = (2*(b*34+Y) + apx)&7
                        int ph = (2 * (b * PADW + y0 + arow + ky)) & 7;
                        int slot = ((q << 2) + quad) ^ ((ph + apx) & 7);
                        Af[m] = *(const bf16x8*)(smem + arow * ROWB +
                                                 apx * 128 + slot * 16);
                    }
#pragma unroll
                    for (int n = 0; n < 4; ++n) {
                        int o = (n << 4) + l15;
                        int slot = ((q << 2) + quad) ^ (l15 & 7);
                        Bf[n] = *(const bf16x8*)(smem + A_LDS + kx * 8192 +
                                                 o * 128 + slot * 16);
                    }
#pragma unroll
                    for (int m = 0; m < 4; ++m)
#pragma unroll
                        for (int n = 0; n < 4; ++n)
                            acc[m][n] = __builtin_amdgcn_mfma_f32_16x16x32_bf16(
                                Af[m], Bf[n], acc[m][n], 0, 0, 0);
                }
        }
    }

    // Epilogue. M(pixel) = quad*4+r (+16 for odd m-tile), N(oc) = n*16+l15.
    if (FINAL) {
        float* out = (float*)dstv;   // fp32 NCHW [128][64][32][32]
#pragma unroll
        for (int m = 0; m < 4; ++m) {
            int row = y0 + 2 * wv + (m >> 1);
#pragma unroll
            for (int n = 0; n < 4; ++n) {
                int o = (n << 4) + l15;
#pragma unroll
                for (int r = 0; r < 4; ++r) {
                    int x = ((m & 1) << 4) + (quad << 2) + r;
                    out[(((size_t)b * 64 + o) * 32 + row) * 32 + x] = acc[m][n][r];
                }
            }
        }
    } else {
        __hip_bfloat16* out = (__hip_bfloat16*)dstv;  // relu -> swizzled NHWC
#pragma unroll
        for (int m = 0; m < 4; ++m) {
            int row = y0 + 2 * wv + (m >> 1);
#pragma unroll
            for (int n = 0; n < 4; ++n) {
                int o = (n << 4) + l15;
#pragma unroll
                for (int r = 0; r < 4; ++r) {
                    int x = ((m & 1) << 4) + (quad << 2) + r;
                    int p = (b * PADW + row + 1) * PADW + x + 1;
                    float v = fmaxf(acc[m][n][r], 0.f);
                    size_t e = (size_t)p * 64 +
                               ((((o >> 3) ^ (p & 7)) << 3) + (o & 7));
                    out[e] = __float2bfloat16(v);
                }
            }
        }
    }
}

// ---------------------------------------------------------------------------
extern "C" void kernel_launch(void* const* d_in, const int* in_sizes, int n_in,
                              void* d_out, int out_size, void* d_ws,
                              size_t ws_size, hipStream_t stream) {
    const float* inputs  = (const float*)d_in[0];
    const float* alphas1 = (const float*)d_in[1];
    const float* alphas2 = (const float*)d_in[2];
    const float* W       = (const float*)d_in[3];
    char* ws = (char*)d_ws;

    __hip_bfloat16* wt = (__hip_bfloat16*)(ws);                     // 442 KB
    __hip_bfloat16* r0 = (__hip_bfloat16*)(ws + ((size_t)1 << 20)); // 18.1 MB
    __hip_bfloat16* r1 = (__hip_bfloat16*)(ws + ((size_t)20 << 20));
    __hip_bfloat16* r2 = (__hip_bfloat16*)(ws + ((size_t)40 << 20));
    float* out = (float*)d_out;

    prep_weights<<<864, 256, 0, stream>>>(alphas1, alphas2, W, wt);
    relu_pad<<<128 * 32, 256, 0, stream>>>(inputs, r0);
    zero_halo<<<128, 256, 0, stream>>>(r0, r1, r2);

    conv_stage<1, false><<<512, 256, 0, stream>>>(r0, r1, r2, wt, (void*)r1, 0);
    conv_stage<2, false><<<512, 256, 0, stream>>>(r0, r1, r2, wt, (void*)r2, 1);
    conv_stage<3, true ><<<512, 256, 0, stream>>>(r0, r1, r2, wt, (void*)out, 3);
}